// Round 2
// 919.159 us; speedup vs baseline: 1.0658x; 1.0658x over previous
//
#include <hip/hip_runtime.h>
#include <hip/hip_bf16.h>

typedef unsigned short u16;
typedef unsigned char u8;
typedef __attribute__((ext_vector_type(8))) short bf16x8;
typedef __attribute__((ext_vector_type(4))) float f32x4;

#define MFMA16(a, b, c) __builtin_amdgcn_mfma_f32_16x16x32_bf16(a, b, c, 0, 0, 0)

// lgkm-only barrier: does NOT drain vmcnt. __syncthreads() lowers to
// s_waitcnt vmcnt(0) expcnt(0) lgkmcnt(0) + s_barrier, which forced a full
// drain of the 32 KB/CU/iter attn stores every iteration (the measured
// serialization: MfmaUtil 4%, VALUBusy 15%, HBM 16%). Cross-wave data here
// is LDS-only, so lgkmcnt(0) is sufficient. asm memory clobbers pin memory
// ops on both sides of the barrier.
#define LGKM_BARRIER()                                     \
    do {                                                   \
        asm volatile("s_waitcnt lgkmcnt(0)" ::: "memory"); \
        __builtin_amdgcn_s_barrier();                      \
        asm volatile("" ::: "memory");                     \
    } while (0)

static __device__ __forceinline__ u16 f2bf(float f) {
    __hip_bfloat16 h = __float2bfloat16(f);
    return *reinterpret_cast<u16*>(&h);
}
static __device__ __forceinline__ float bf2f(u16 h) {
    unsigned u = ((unsigned)h) << 16;
    return __uint_as_float(u);
}

// ---------------------------------------------------------------------------
// Kernel A: elementwise K fp32 -> bf16 into scratch (same [B,L,N,D] layout).
// ---------------------------------------------------------------------------
__global__ __launch_bounds__(256) void kconv_kernel(const float* __restrict__ kf,
                                                    u16* __restrict__ kb) {
    const size_t i = ((size_t)blockIdx.x * 256 + threadIdx.x) * 4;
    float4 f = *(const float4*)(kf + i);
    alignas(8) u16 w[4] = {f2bf(f.x), f2bf(f.y), f2bf(f.z), f2bf(f.w)};
    *(uint2*)(kb + i) = *(const uint2*)w;
}

// ---------------------------------------------------------------------------
// Kernel B: V fp32 [B,L,N,D] -> VT bf16 [B,N,D,L] (transpose + convert) so PV
// B-fragments are contiguous-in-j 16B loads.
// ---------------------------------------------------------------------------
__global__ __launch_bounds__(256) void vt_kernel(const float* __restrict__ v,
                                                 u16* __restrict__ vt) {
    __shared__ u16 T[64][72];
    const int t = threadIdx.x, bid = blockIdx.x;
    const int b = bid >> 9, n = bid & 15, j0 = ((bid >> 4) & 31) << 6;
    {
        const int jj = t >> 4, tt = t & 15;
#pragma unroll
        for (int rep = 0; rep < 4; rep++) {
            const int j = rep * 16 + jj;
            const float* src = v + (((size_t)((b * 2048 + j0 + j) * 16 + n)) << 6) + tt * 4;
            float4 f = *(const float4*)src;
            alignas(8) u16 w[4] = {f2bf(f.x), f2bf(f.y), f2bf(f.z), f2bf(f.w)};
            *(uint2*)&T[j][tt * 4] = *(const uint2*)w;
        }
    }
    __syncthreads();
    {
        const int d = t >> 2, jq = t & 3;
        alignas(16) u16 w[16];
#pragma unroll
        for (int e = 0; e < 16; e++) w[e] = T[jq * 16 + e][d];
        u16* dst = vt + (((size_t)((b * 16 + n) * 64 + d)) << 11) + j0 + jq * 16;
        *(uint4*)dst = *(const uint4*)&w[0];
        *(uint4*)(dst + 8) = *(const uint4*)&w[8];
    }
}

// ---------------------------------------------------------------------------
// Main fused attention kernel. fp32 outputs.
// Grid: 256 WGs. Block: 1024 threads = 16 waves = 16 heads.
// ---------------------------------------------------------------------------
__global__ __launch_bounds__(1024, 4) void attn_kernel(
    const float* __restrict__ qf, const u16* __restrict__ kb_g,
    const u16* __restrict__ vt, const void* __restrict__ mask,
    float* __restrict__ ctx, float* __restrict__ attn) {
    __shared__ u16 maskT[2048];           // bit i of maskT[j]: mask[b][i0+i][j]
    __shared__ u16 pbuf[2][16][16][40];   // parity-double-buffered: 1 barrier/iter

    const int tid = threadIdx.x;
    const int lane = tid & 63;
    const int wv = tid >> 6;  // head index
    const int g = lane >> 4, c = lane & 15;
    const int rbit = g * 4;

    const int bid = blockIdx.x;
    const int b = ((bid & 7) < 4) ? 0 : 1;             // XCDs 0-3: b=0, 4-7: b=1
    const int idx = ((bid >> 3) << 2) | (bid & 3);     // 0..127
    const int i0 = idx << 4;

    // --- probe mask dtype (wave-uniform) ---
    bool mask_is_u8;
    {
        unsigned acc = 0;
        const unsigned* mw = (const unsigned*)mask;
#pragma unroll
        for (int i = 0; i < 64; i++) acc |= mw[i];
        mask_is_u8 = (acc & 0xFFFFFF00u) != 0u;
    }

    // --- build mask bitmap (thread t covers j = 2t, 2t+1) ---
    {
        const size_t base = ((size_t)(b * 2048 + i0)) * 2048 + (size_t)tid * 2;
        unsigned m0 = 0, m1 = 0;
        if (mask_is_u8) {
            const u8* m8 = (const u8*)mask;
#pragma unroll
            for (int i = 0; i < 16; i++) {
                const u8* mp = m8 + base + (size_t)i * 2048;
                if (mp[0]) m0 |= (1u << i);
                if (mp[1]) m1 |= (1u << i);
            }
        } else {
            const int* m32 = (const int*)mask;
#pragma unroll
            for (int i = 0; i < 16; i++) {
                const int* mp = m32 + base + (size_t)i * 2048;
                if (mp[0]) m0 |= (1u << i);
                if (mp[1]) m1 |= (1u << i);
            }
        }
        *reinterpret_cast<unsigned*>(&maskT[tid * 2]) = m0 | (m1 << 16);
    }
    __syncthreads();  // once, outside the hot loops: full drain is fine here

    // --- Q fragments (A-operand): lane holds Q[i0+c][d = g*8.. (+32)], fp32->bf16 ---
    bf16x8 aq0, aq1;
    {
        const float* qp = qf + (((size_t)(b * 2048 + i0 + c) * 16 + wv) << 6) + g * 8;
        float4 f0 = *(const float4*)qp;
        float4 f1 = *(const float4*)(qp + 4);
        float4 f2 = *(const float4*)(qp + 32);
        float4 f3 = *(const float4*)(qp + 36);
        alignas(16) u16 w0[8] = {f2bf(f0.x), f2bf(f0.y), f2bf(f0.z), f2bf(f0.w),
                                 f2bf(f1.x), f2bf(f1.y), f2bf(f1.z), f2bf(f1.w)};
        alignas(16) u16 w1[8] = {f2bf(f2.x), f2bf(f2.y), f2bf(f2.z), f2bf(f2.w),
                                 f2bf(f3.x), f2bf(f3.y), f2bf(f3.z), f2bf(f3.w)};
        aq0 = *(const bf16x8*)w0;
        aq1 = *(const bf16x8*)w1;
    }

    const u16* kb = kb_g + (((size_t)(b * 2048) * 16 + wv) << 6) + g * 8;
    const u16* vb = vt + (((size_t)(b * 16 + wv)) << 17);  // [b][n] plane, 64*2048

    // =================== Pass 1: row sums of exp ===================
    float l0 = 0.f, l1 = 0.f, l2 = 0.f, l3 = 0.f;
    for (int j0 = 0; j0 < 2048; j0 += 16) {
        const u16* kp = kb + (size_t)(j0 + c) * 1024;
        bf16x8 b0 = *(const bf16x8*)kp;
        bf16x8 b1 = *(const bf16x8*)(kp + 32);
        f32x4 s = {0.f, 0.f, 0.f, 0.f};
        s = MFMA16(aq0, b0, s);
        s = MFMA16(aq1, b1, s);
        const unsigned mt = maskT[j0 + c];
        l0 += __expf(((mt >> (rbit + 0)) & 1) ? -1e9f : s[0] * 0.125f);
        l1 += __expf(((mt >> (rbit + 1)) & 1) ? -1e9f : s[1] * 0.125f);
        l2 += __expf(((mt >> (rbit + 2)) & 1) ? -1e9f : s[2] * 0.125f);
        l3 += __expf(((mt >> (rbit + 3)) & 1) ? -1e9f : s[3] * 0.125f);
    }
#pragma unroll
    for (int off = 1; off <= 8; off <<= 1) {
        l0 += __shfl_xor(l0, off);
        l1 += __shfl_xor(l1, off);
        l2 += __shfl_xor(l2, off);
        l3 += __shfl_xor(l3, off);
    }
    const float n0i = (l0 != 0.f) ? 1.f / l0 : 0.f;
    const float n1i = (l1 != 0.f) ? 1.f / l1 : 0.f;
    const float n2i = (l2 != 0.f) ? 1.f / l2 : 0.f;
    const float n3i = (l3 != 0.f) ? 1.f / l3 : 0.f;

    // =================== Pass 2: write P, accumulate PV ===================
    f32x4 o0 = {0.f, 0.f, 0.f, 0.f}, o1 = o0, o2 = o0, o3 = o0;

    const int wo_i = tid >> 6;
    const int wo_c = tid & 63;
    const int wo_j = wo_c >> 1;
    const int wo_n = (wo_c & 1) << 3;
    float* attn_row = attn + (((size_t)(b * 2048 + i0 + wo_i)) << 15) + wo_n;

    // Prefetch iteration 0's K (both 16-col subs) and V into registers.
    bf16x8 ck0a, ck0b, ck1a, ck1b, cv0, cv1, cv2, cv3;
    {
        const u16* kp0 = kb + (size_t)c * 1024;
        ck0a = *(const bf16x8*)kp0;
        ck0b = *(const bf16x8*)(kp0 + 32);
        const u16* kp1 = kb + (size_t)(16 + c) * 1024;
        ck1a = *(const bf16x8*)kp1;
        ck1b = *(const bf16x8*)(kp1 + 32);
        const u16* vp = vb + (size_t)c * 2048 + g * 8;
        cv0 = *(const bf16x8*)(vp);
        cv1 = *(const bf16x8*)(vp + 16 * 2048);
        cv2 = *(const bf16x8*)(vp + 32 * 2048);
        cv3 = *(const bf16x8*)(vp + 48 * 2048);
    }

    int p = 0;
    for (int j0 = 0; j0 < 2048; j0 += 32, p ^= 1) {
        // ---- QK^T for 32 columns from prefetched K registers ----
        {
            f32x4 s = {0.f, 0.f, 0.f, 0.f};
            s = MFMA16(aq0, ck0a, s);
            s = MFMA16(aq1, ck0b, s);
            const unsigned mt = maskT[j0 + c];
            pbuf[p][wv][rbit + 0][c] =
                f2bf(__expf(((mt >> (rbit + 0)) & 1) ? -1e9f : s[0] * 0.125f) * n0i);
            pbuf[p][wv][rbit + 1][c] =
                f2bf(__expf(((mt >> (rbit + 1)) & 1) ? -1e9f : s[1] * 0.125f) * n1i);
            pbuf[p][wv][rbit + 2][c] =
                f2bf(__expf(((mt >> (rbit + 2)) & 1) ? -1e9f : s[2] * 0.125f) * n2i);
            pbuf[p][wv][rbit + 3][c] =
                f2bf(__expf(((mt >> (rbit + 3)) & 1) ? -1e9f : s[3] * 0.125f) * n3i);
        }
        {
            f32x4 s = {0.f, 0.f, 0.f, 0.f};
            s = MFMA16(aq0, ck1a, s);
            s = MFMA16(aq1, ck1b, s);
            const unsigned mt = maskT[j0 + 16 + c];
            pbuf[p][wv][rbit + 0][16 + c] =
                f2bf(__expf(((mt >> (rbit + 0)) & 1) ? -1e9f : s[0] * 0.125f) * n0i);
            pbuf[p][wv][rbit + 1][16 + c] =
                f2bf(__expf(((mt >> (rbit + 1)) & 1) ? -1e9f : s[1] * 0.125f) * n1i);
            pbuf[p][wv][rbit + 2][16 + c] =
                f2bf(__expf(((mt >> (rbit + 2)) & 1) ? -1e9f : s[2] * 0.125f) * n2i);
            pbuf[p][wv][rbit + 3][16 + c] =
                f2bf(__expf(((mt >> (rbit + 3)) & 1) ? -1e9f : s[3] * 0.125f) * n3i);
        }
        LGKM_BARRIER();

        // own-head P fragment (A-operand) for PV
        const bf16x8 ap = *(const bf16x8*)&pbuf[p][wv][c][g * 8];

        // ---- prefetch next iteration's K and V BEFORE this iteration's attn
        // stores are issued: vmcnt retires in order, so any wait for a load
        // issued after the stores would drain the stores too. Loads issued
        // before the stores keep them outstanding across iterations. ----
        const int jn = (j0 + 32) & 2047;  // clamped in-bounds; last-iter values unused
        bf16x8 nk0a, nk0b, nk1a, nk1b, nv0, nv1, nv2, nv3;
        {
            const u16* kp0 = kb + (size_t)(jn + c) * 1024;
            nk0a = *(const bf16x8*)kp0;
            nk0b = *(const bf16x8*)(kp0 + 32);
            const u16* kp1 = kb + (size_t)(jn + 16 + c) * 1024;
            nk1a = *(const bf16x8*)kp1;
            nk1b = *(const bf16x8*)(kp1 + 32);
            const u16* vp = vb + (size_t)c * 2048 + jn + g * 8;
            nv0 = *(const bf16x8*)(vp);
            nv1 = *(const bf16x8*)(vp + 16 * 2048);
            nv2 = *(const bf16x8*)(vp + 32 * 2048);
            nv3 = *(const bf16x8*)(vp + 48 * 2048);
        }

        // PV from current (previous-iter prefetched) V registers
        o0 = MFMA16(ap, cv0, o0);
        o1 = MFMA16(ap, cv1, o1);
        o2 = MFMA16(ap, cv2, o2);
        o3 = MFMA16(ap, cv3, o3);

        // pin issue order: prefetch loads must precede the stores below
        __builtin_amdgcn_sched_barrier(0);

        // ---- coalesced fp32 attention write: gather across heads, 32 B/thread.
        // Nontemporal: 536 MB write-once stream must not thrash the 4 MB/XCD L2
        // that is serving the K/V re-reads. (f32x4 = native clang vector; HIP's
        // float4 class type is rejected by the builtin.) ----
        {
            alignas(16) float w[8];
#pragma unroll
            for (int e = 0; e < 8; e++) w[e] = bf2f(pbuf[p][wo_n + e][wo_i][wo_j]);
            float* dst = attn_row + (size_t)(j0 + wo_j) * 16;
            __builtin_nontemporal_store(*(const f32x4*)&w[0], (f32x4*)dst);
            __builtin_nontemporal_store(*(const f32x4*)&w[4], (f32x4*)(dst + 4));
        }

        ck0a = nk0a; ck0b = nk0b; ck1a = nk1a; ck1b = nk1b;
        cv0 = nv0; cv1 = nv1; cv2 = nv2; cv3 = nv3;
    }

    // --- context epilogue (fp32): O[i = rbit+r][d = dt*16 + c] ---
#pragma unroll
    for (int r = 0; r < 4; r++) {
        float* cp = ctx + (((size_t)(b * 2048 + i0 + rbit + r) * 16 + wv) << 6) + c;
        cp[0]  = o0[r];
        cp[16] = o1[r];
        cp[32] = o2[r];
        cp[48] = o3[r];
    }
}

extern "C" void kernel_launch(void* const* d_in, const int* in_sizes, int n_in,
                              void* d_out, int out_size, void* d_ws, size_t ws_size,
                              hipStream_t stream) {
    const float* q   = (const float*)d_in[0];
    const float* k   = (const float*)d_in[1];
    const float* v   = (const float*)d_in[2];
    const void* mask = (const void*)d_in[3];

    float* ctx  = (float*)d_out;               // 2*2048*16*64    = 4,194,304 floats
    float* attn = (float*)d_out + 4194304;     // 2*2048*2048*16  = 134,217,728 floats

    u16* vt = (u16*)d_ws;                      // 8.39 MB bf16 VT [B,N,D,L]
    u16* kb = vt + 4194304;                    // 8.39 MB bf16 K  [B,L,N,D]

    kconv_kernel<<<4096, 256, 0, stream>>>(k, kb);
    vt_kernel<<<1024, 256, 0, stream>>>(v, vt);
    attn_kernel<<<256, 1024, 0, stream>>>(q, kb, vt, mask, ctx, attn);
}